// Round 1
// baseline (149.304 us; speedup 1.0000x reference)
//
#include <hip/hip_runtime.h>
#include <hip/hip_bf16.h>
#include <stdint.h>

// MSDeformableAttention3D: bs=1, nq=40000, embed=256, H=8 heads, L=4 levels, P=4 points,
// num_kv=16 total value rows (levels use rows [0,14)), d=32 channels/head.
//
// Pipeline:
//  k_transpose: W_T[n][k] = W_so[k][n]           (for k-contiguous B fragments)
//  k_scores:    raw attention scores (fp32) -> ws rows [512..1024)
//  k_gemm:      off = query @ W_so + b_so (bf16 MFMA) -> ws rows [0..512) as bf16
//  k_samp:      softmax + location remap + bilinear sample + weighted sum -> out
//
// ws layout: [0,256KB) W_T fp32; [256KB, 256KB+40000*1024) per-query rows
//   row q: bytes [0,512) = 256 x bf16 offsets, [512,1024) = 128 x f32 scores

#define NQ 40000
#define ROW_BYTES 1024
#define ROWS_OFF (256 * 1024)

typedef __attribute__((ext_vector_type(8))) short short8;
typedef __attribute__((ext_vector_type(4))) float float4_;

static __device__ __forceinline__ uint16_t f2bf(float f) {
    union { float f; uint32_t u; } a; a.f = f;
    uint32_t r = a.u + 0x7fffu + ((a.u >> 16) & 1u);   // RNE
    return (uint16_t)(r >> 16);
}
static __device__ __forceinline__ float bf2f(uint32_t bits16) {
    union { uint32_t u; float f; } a; a.u = bits16 << 16;
    return a.f;
}

// ---------------- K0: transpose W_so (256x256) ----------------
__global__ __launch_bounds__(256) void k_transpose(const float* __restrict__ W,
                                                   float* __restrict__ WT) {
    int n = blockIdx.x;      // output row = W_so column
    int k = threadIdx.x;
    WT[n * 256 + k] = W[k * 256 + n];
}

// ---------------- K_scores: fp32 q.k per head ----------------
// grid 2500, block 256; 16 queries per block
__global__ __launch_bounds__(256) void k_scores(const float* __restrict__ q,
                                                const float* __restrict__ key,
                                                char* __restrict__ rows) {
    __shared__ float qt[16 * 256];
    int t = threadIdx.x;
    int qbase = blockIdx.x * 16;
    {   // stage 16 query rows (1024 float4, 4 per thread)
        const float4_* qsrc = (const float4_*)(q + (size_t)qbase * 256);
        float4_* qdst = (float4_*)qt;
        for (int i = 0; i < 4; ++i) qdst[i * 256 + t] = qsrc[i * 256 + t];
    }
    int q2 = t >> 7;          // 0..1
    int h  = (t >> 4) & 7;    // 0..7
    int kk = t & 15;          // key index 0..15
    float4_ kv[8];
    {
        const float4_* ksrc = (const float4_*)(key + kk * 256 + h * 32);
        for (int j = 0; j < 8; ++j) kv[j] = ksrc[j];
    }
    __syncthreads();
    for (int i = 0; i < 8; ++i) {
        int qi = q2 + i * 2;
        const float4_* qp = (const float4_*)(qt + qi * 256 + h * 32);
        float acc = 0.f;
        for (int j = 0; j < 8; ++j) {
            float4_ v = qp[j];
            acc += v.x * kv[j].x + v.y * kv[j].y + v.z * kv[j].z + v.w * kv[j].w;
        }
        float* srow = (float*)(rows + (size_t)(qbase + qi) * ROW_BYTES + 512);
        srow[h * 16 + kk] = acc;
    }
}

// ---------------- K_gemm: off = query @ W_so + b_so (bf16 MFMA) ----------------
// grid 625, block 512 (8 waves). BM=64, BN=256, BK=32, 8 K-steps.
// wave w: rows (w>>2)*32.., cols (w&3)*64..  acc[2][4] 16x16 tiles.
#define LDSTR 48   // padded LDS row stride (shorts), 96B: 16B-aligned, reduces bank conflicts
__global__ __launch_bounds__(512) void k_gemm(const float* __restrict__ q,
                                              const float* __restrict__ WT,
                                              const float* __restrict__ bso,
                                              char* __restrict__ rows) {
    __shared__ short A[64 * LDSTR];
    __shared__ short B[256 * LDSTR];
    int t = threadIdx.x;
    int qbase = blockIdx.x * 64;
    int w = t >> 6, l = t & 63;
    int wm = w >> 2, wn = w & 3;
    float4_ acc[2][4];
    for (int i = 0; i < 2; ++i)
        for (int j = 0; j < 4; ++j) acc[i][j] = (float4_)0.f;

    int ar = t >> 3, ak = t & 7;       // A staging: row 0..63, float4-col 0..7
    int lrow = l & 15, lk = (l >> 4) * 8;

    for (int ks = 0; ks < 8; ++ks) {
        __syncthreads();
        {   // stage A: 64x32 (1 float4/thread)
            float4_ v = *(const float4_*)(q + (size_t)(qbase + ar) * 256 + ks * 32 + ak * 4);
            uint32_t p0 = (uint32_t)f2bf(v.x) | ((uint32_t)f2bf(v.y) << 16);
            uint32_t p1 = (uint32_t)f2bf(v.z) | ((uint32_t)f2bf(v.w) << 16);
            uint32_t* dst = (uint32_t*)&A[ar * LDSTR + ak * 4];
            dst[0] = p0; dst[1] = p1;
        }
        for (int i = 0; i < 4; ++i) {   // stage B: 256x32 transposed-source (4 float4/thread)
            int bn = i * 64 + (t >> 3);
            float4_ v = *(const float4_*)(WT + (size_t)bn * 256 + ks * 32 + ak * 4);
            uint32_t p0 = (uint32_t)f2bf(v.x) | ((uint32_t)f2bf(v.y) << 16);
            uint32_t p1 = (uint32_t)f2bf(v.z) | ((uint32_t)f2bf(v.w) << 16);
            uint32_t* dst = (uint32_t*)&B[bn * LDSTR + ak * 4];
            dst[0] = p0; dst[1] = p1;
        }
        __syncthreads();
        short8 af[2], bf[4];
        for (int mi = 0; mi < 2; ++mi)
            af[mi] = *(const short8*)&A[(wm * 32 + mi * 16 + lrow) * LDSTR + lk];
        for (int ni = 0; ni < 4; ++ni)
            bf[ni] = *(const short8*)&B[(wn * 64 + ni * 16 + lrow) * LDSTR + lk];
        for (int mi = 0; mi < 2; ++mi)
            for (int ni = 0; ni < 4; ++ni)
                acc[mi][ni] = __builtin_amdgcn_mfma_f32_16x16x32_bf16(
                    af[mi], bf[ni], acc[mi][ni], 0, 0, 0);
    }
    // epilogue: +bias, store bf16 into ws rows
    int lq4 = (l >> 4) * 4;
    for (int mi = 0; mi < 2; ++mi)
        for (int ni = 0; ni < 4; ++ni) {
            int col = wn * 64 + ni * 16 + lrow;
            float b = bso[col];
            int qrow = qbase + wm * 32 + mi * 16 + lq4;
            for (int r = 0; r < 4; ++r) {
                float vv = acc[mi][ni][r] + b;
                *(uint16_t*)(rows + (size_t)(qrow + r) * ROW_BYTES + col * 2) = f2bf(vv);
            }
        }
}

// ---------------- K_samp: softmax + remap + bilinear + weighted sum ----------------
// grid 1250, block 256; 32 queries/block, 2 per A/B step.
// Faithful (p,l)->(l,p) reshape: for (h,lev,p): off col = 2*(h*16+lev*4+p),
// ref/norm indexed by p, sampling grid/start indexed by lev, attn k = lev*4+p.
__global__ __launch_bounds__(256) void k_samp(const char* __restrict__ rows,
                                              const float* __restrict__ value,
                                              const float* __restrict__ refp,
                                              const int* __restrict__ sshapes,
                                              float* __restrict__ out) {
    __shared__ float vlds[17 * 256];   // row 16 = zeros (padding target)
    __shared__ float wbuf[256 * 8];    // per (q2,h,lp): aw[4] + idx[4]
    int t = threadIdx.x;
    {   // stage value (16x256) + zero row
        float4_* vd = (float4_*)vlds;
        const float4_* vs = (const float4_*)value;
        for (int i = 0; i < 4; ++i) vd[i * 256 + t] = vs[i * 256 + t];
        vlds[4096 + t] = 0.f;
    }
    int Hl_[4], Wl_[4], st_[4];
    {
        int s = 0;
        for (int l2 = 0; l2 < 4; ++l2) {
            Hl_[l2] = sshapes[2 * l2];
            Wl_[l2] = sshapes[2 * l2 + 1];
            st_[l2] = s;
            s += Hl_[l2] * Wl_[l2];
        }
    }
    int q2 = t >> 7, h = (t >> 4) & 7, lp = t & 15, lev = lp >> 2, pp = lp & 3;
    int qbase = blockIdx.x * 32;
    __syncthreads();

    for (int it = 0; it < 16; ++it) {
        // ---- step A: one (q2,h,lev,p) per thread ----
        int qa = qbase + it * 2 + q2;
        const char* rp = rows + (size_t)qa * ROW_BYTES;
        float s = *(const float*)(rp + 512 + (h * 16 + lp) * 4);
        float m = s;
        for (int d2 = 1; d2 < 16; d2 <<= 1) m = fmaxf(m, __shfl_xor(m, d2));
        float e = __expf(s - m);
        float sum = e;
        for (int d2 = 1; d2 < 16; d2 <<= 1) sum += __shfl_xor(sum, d2);
        float attn = e / sum;

        uint32_t ob = *(const uint32_t*)(rp + (h * 16 + lp) * 4);  // off col 2g, 2g+1
        float ox = bf2f(ob & 0xffffu);
        float oy = bf2f(ob >> 16);
        float2 rv = *(const float2*)(refp + ((size_t)qa * 4 + pp) * 2);
        float locx = rv.x + ox / (float)Wl_[pp];
        float locy = rv.y + oy / (float)Hl_[pp];
        int Wl = Wl_[lev], Hl = Hl_[lev], st = st_[lev];
        float x = locx * (float)Wl - 0.5f;
        float y = locy * (float)Hl - 0.5f;
        float x0f = floorf(x), y0f = floorf(y);
        float fx = x - x0f, fy = y - y0f;
        int ix0 = (int)x0f, iy0 = (int)y0f;
        int ix1 = ix0 + 1, iy1 = iy0 + 1;
        bool vx0 = (ix0 >= 0) & (ix0 < Wl), vx1 = (ix1 >= 0) & (ix1 < Wl);
        bool vy0 = (iy0 >= 0) & (iy0 < Hl), vy1 = (iy1 >= 0) & (iy1 < Hl);
        int i00 = (vx0 & vy0) ? st + iy0 * Wl + ix0 : 16;
        int i10 = (vx1 & vy0) ? st + iy0 * Wl + ix1 : 16;
        int i01 = (vx0 & vy1) ? st + iy1 * Wl + ix0 : 16;
        int i11 = (vx1 & vy1) ? st + iy1 * Wl + ix1 : 16;
        float* wb = &wbuf[t * 8];
        wb[0] = attn * (1.f - fx) * (1.f - fy);
        wb[1] = attn * fx * (1.f - fy);
        wb[2] = attn * (1.f - fx) * fy;
        wb[3] = attn * fx * fy;
        ((int*)wb)[4] = i00; ((int*)wb)[5] = i10;
        ((int*)wb)[6] = i01; ((int*)wb)[7] = i11;
        __syncthreads();

        // ---- step B: thread = (h,c); c-consecutive -> conflict-free gathers ----
        int hB = t >> 5;
        for (int qq = 0; qq < 2; ++qq) {
            float acc = 0.f;
            const float* wbr = &wbuf[(qq * 128 + hB * 16) * 8];
            for (int s2 = 0; s2 < 16; ++s2) {
                float4_ aw = *(const float4_*)(wbr + s2 * 8);
                const int* id = (const int*)(wbr + s2 * 8 + 4);
                acc += aw.x * vlds[id[0] * 256 + t];   // t = hB*32 + c
                acc += aw.y * vlds[id[1] * 256 + t];
                acc += aw.z * vlds[id[2] * 256 + t];
                acc += aw.w * vlds[id[3] * 256 + t];
            }
            out[(size_t)(qbase + it * 2 + qq) * 256 + t] = acc;
        }
        __syncthreads();
    }
}

extern "C" void kernel_launch(void* const* d_in, const int* in_sizes, int n_in,
                              void* d_out, int out_size, void* d_ws, size_t ws_size,
                              hipStream_t stream) {
    (void)in_sizes; (void)n_in; (void)out_size; (void)ws_size;
    const float* query = (const float*)d_in[0];
    const float* key   = (const float*)d_in[1];
    const float* value = (const float*)d_in[2];
    const float* refp  = (const float*)d_in[3];
    const int*   ss    = (const int*)d_in[4];
    const float* Wso   = (const float*)d_in[5];
    const float* bso   = (const float*)d_in[6];
    char* ws = (char*)d_ws;
    float* WT = (float*)ws;
    char* rows = ws + ROWS_OFF;

    hipLaunchKernelGGL(k_transpose, dim3(256), dim3(256), 0, stream, Wso, WT);
    hipLaunchKernelGGL(k_scores, dim3(2500), dim3(256), 0, stream, query, key, rows);
    hipLaunchKernelGGL(k_gemm, dim3(625), dim3(512), 0, stream, query, WT, bso, rows);
    hipLaunchKernelGGL(k_samp, dim3(1250), dim3(256), 0, stream, rows, value, refp, ss,
                       (float*)d_out);
}

// Round 2
// 86.921 us; speedup vs baseline: 1.7177x; 1.7177x over previous
//
#include <hip/hip_runtime.h>
#include <hip/hip_bf16.h>
#include <stdint.h>

// MSDeformableAttention3D fused: bs=1, nq=40000=625*64, embed=256, H=8, L=4, P=4,
// 16 value rows, d=32. One block = 64 queries, 512 threads (8 waves).
// Wave w <-> head w, lane l <-> query l for scores/sampling phases.
//
// Phases: 0) stage value^T bf16 (rows 16..31 zeroed)  1) fp32 scores + in-lane
// softmax  2) off = q@W_so+b (bf16 MFMA, 64x256)  3) epilogue -> sOff LDS +
// zero wsum  4) sampling: corner weights scatter-reduced into per-(q,h) 16-bin
// wsum (value has only 16 rows -> output is wsum @ value)  5) final MFMA
// (64x32 @ 32x32 per head) + coalesced-ish store.

typedef __attribute__((ext_vector_type(8))) short short8;
typedef __attribute__((ext_vector_type(4))) float float4_;

#define LDSTR  40      // GEMM/value^T LDS row stride (shorts): 80B -> 2-way-free banks
#define OFFSTR 264     // sOff row stride (shorts): 528B, 16B-aligned
#define SB_OFF 5120
#define SW_OFF 33792   // wsum fp32 [512][17]
#define VT_OFF 68608   // value^T bf16 [256][LDSTR]
#define SMEM_BYTES 89088

static __device__ __forceinline__ uint16_t f2bf(float f) {
    union { float f; uint32_t u; } a; a.f = f;
    uint32_t r = a.u + 0x7fffu + ((a.u >> 16) & 1u);   // RNE
    return (uint16_t)(r >> 16);
}
static __device__ __forceinline__ float bf2f(uint16_t b) {
    union { uint32_t u; float f; } a; a.u = ((uint32_t)b) << 16;
    return a.f;
}

// ---------------- W_so^T as bf16 (256x256) ----------------
__global__ __launch_bounds__(256) void k_transpose(const float* __restrict__ W,
                                                   uint16_t* __restrict__ WTb) {
    int n = blockIdx.x, k = threadIdx.x;
    WTb[n * 256 + k] = f2bf(W[k * 256 + n]);
}

// ---------------- fused kernel ----------------
__global__ __launch_bounds__(512) void k_fused(const float* __restrict__ q,
                                               const float* __restrict__ key,
                                               const float* __restrict__ value,
                                               const float* __restrict__ refp,
                                               const int* __restrict__ sshapes,
                                               const uint16_t* __restrict__ WTb,
                                               const float* __restrict__ bso,
                                               float* __restrict__ out) {
    __shared__ __align__(16) char smem[SMEM_BYTES];
    short* sA   = (short*)(smem);            // GEMM A tile   (dead after K-loop)
    short* sB   = (short*)(smem + SB_OFF);   // GEMM B tile   (dead after K-loop)
    short* sOff = (short*)(smem);            // off bf16 [64][OFFSTR] (reuses A/B)
    float* sW   = (float*)(smem + SW_OFF);   // wsum fp32 [512][17]
    short* sVT  = (short*)(smem + VT_OFF);   // value^T bf16 [256][LDSTR]

    int t = threadIdx.x;
    int w = t >> 6, l = t & 63;
    int qbase = blockIdx.x * 64;
    int qa = qbase + l;

    // ---- phase 0: value^T bf16, zero-pad k rows 16..31 ----
#pragma unroll
    for (int j = 0; j < 8; ++j) {
        int i = t * 8 + j;                       // value[r][c], r=i>>8, c=i&255
        sVT[(i & 255) * LDSTR + (i >> 8)] = (short)f2bf(value[i]);
    }
#pragma unroll
    for (int j = 0; j < 8; ++j) {
        int i = t * 8 + j;                       // 256 cols x 16 zero rows
        sVT[(i >> 4) * LDSTR + 16 + (i & 15)] = 0;
    }

    // ---- phase 1: fp32 scores (lane=query, wave=head) + in-lane softmax ----
    float sc[16];
    {
        const float4_* qp = (const float4_*)(q + (size_t)qa * 256 + w * 32);
        float4_ qv[8];
#pragma unroll
        for (int j = 0; j < 8; ++j) qv[j] = qp[j];
#pragma unroll
        for (int kk = 0; kk < 16; ++kk) {
            const float4_* kp = (const float4_*)(key + kk * 256 + w * 32);
            float a = 0.f;
#pragma unroll
            for (int j = 0; j < 8; ++j) {
                float4_ kv = kp[j];
                a += qv[j].x * kv.x + qv[j].y * kv.y + qv[j].z * kv.z + qv[j].w * kv.w;
            }
            sc[kk] = a;
        }
        float m = sc[0];
#pragma unroll
        for (int kk = 1; kk < 16; ++kk) m = fmaxf(m, sc[kk]);
        float s = 0.f;
#pragma unroll
        for (int kk = 0; kk < 16; ++kk) { sc[kk] = __expf(sc[kk] - m); s += sc[kk]; }
        float inv = 1.f / s;
#pragma unroll
        for (int kk = 0; kk < 16; ++kk) sc[kk] *= inv;
    }

    // ---- phase 2: off-GEMM 64x256, bf16 MFMA ----
    int wm = w >> 2, wn = w & 3, lrow = l & 15, lk = (l >> 4) * 8;
    int ar = t >> 3, ak = t & 7;         // A staging
    int bn = t >> 1, bh = (t & 1) * 16;  // B staging
    float4_ acc[2][4];
#pragma unroll
    for (int i = 0; i < 2; ++i)
#pragma unroll
        for (int j = 0; j < 4; ++j) acc[i][j] = (float4_)0.f;

    for (int ks = 0; ks < 8; ++ks) {
        __syncthreads();
        {   // A: 64x32 fp32 -> bf16
            float4_ v = *(const float4_*)(q + (size_t)(qbase + ar) * 256 + ks * 32 + ak * 4);
            uint32_t p0 = (uint32_t)f2bf(v.x) | ((uint32_t)f2bf(v.y) << 16);
            uint32_t p1 = (uint32_t)f2bf(v.z) | ((uint32_t)f2bf(v.w) << 16);
            uint32_t* dst = (uint32_t*)&sA[ar * LDSTR + ak * 4];
            dst[0] = p0; dst[1] = p1;
        }
        {   // B: 256x32 bf16 copy
            const short8* src = (const short8*)(WTb + bn * 256 + ks * 32 + bh);
            *(short8*)&sB[bn * LDSTR + bh]     = src[0];
            *(short8*)&sB[bn * LDSTR + bh + 8] = src[1];
        }
        __syncthreads();
        short8 af[2], bf[4];
#pragma unroll
        for (int mi = 0; mi < 2; ++mi)
            af[mi] = *(const short8*)&sA[(wm * 32 + mi * 16 + lrow) * LDSTR + lk];
#pragma unroll
        for (int ni = 0; ni < 4; ++ni)
            bf[ni] = *(const short8*)&sB[(wn * 64 + ni * 16 + lrow) * LDSTR + lk];
#pragma unroll
        for (int mi = 0; mi < 2; ++mi)
#pragma unroll
            for (int ni = 0; ni < 4; ++ni)
                acc[mi][ni] = __builtin_amdgcn_mfma_f32_16x16x32_bf16(
                    af[mi], bf[ni], acc[mi][ni], 0, 0, 0);
    }
    __syncthreads();

    // ---- phase 3: epilogue (acc+bias -> sOff bf16), zero own wsum bins ----
    {
        int lq4 = (l >> 4) * 4;
#pragma unroll
        for (int mi = 0; mi < 2; ++mi)
#pragma unroll
            for (int ni = 0; ni < 4; ++ni) {
                int col = wn * 64 + ni * 16 + lrow;
                float b = bso[col];
                int qrow = wm * 32 + mi * 16 + lq4;
#pragma unroll
                for (int r = 0; r < 4; ++r)
                    sOff[(qrow + r) * OFFSTR + col] = (short)f2bf(acc[mi][ni][r] + b);
            }
#pragma unroll
        for (int j = 0; j < 17; ++j) sW[t * 17 + j] = 0.f;
    }
    __syncthreads();

    // ---- phase 4: sampling -> scatter into own 16-bin wsum ----
    {
        int Hl[4], Wl[4], stl[4];
        {
            int s0 = 0;
#pragma unroll
            for (int lv = 0; lv < 4; ++lv) {
                Hl[lv] = sshapes[2 * lv];
                Wl[lv] = sshapes[2 * lv + 1];
                stl[lv] = s0;
                s0 += Hl[lv] * Wl[lv];
            }
        }
        union OvU { short8 v; short s[8]; } ov[4];
#pragma unroll
        for (int i = 0; i < 4; ++i)
            ov[i].v = *(const short8*)&sOff[l * OFFSTR + w * 32 + i * 8];
        float4_ r01 = *(const float4_*)(refp + (size_t)qa * 8);
        float4_ r23 = *(const float4_*)(refp + (size_t)qa * 8 + 4);
        float rx[4] = {r01.x, r01.z, r23.x, r23.z};
        float ry[4] = {r01.y, r01.w, r23.y, r23.w};
        float* wb = sW + t * 17;
#pragma unroll
        for (int lp = 0; lp < 16; ++lp) {
            const int lev = lp >> 2, pp = lp & 3;
            float ox = bf2f((uint16_t)ov[(2 * lp) >> 3].s[(2 * lp) & 7]);
            float oy = bf2f((uint16_t)ov[(2 * lp + 1) >> 3].s[(2 * lp + 1) & 7]);
            float locx = rx[pp] + ox / (float)Wl[pp];
            float locy = ry[pp] + oy / (float)Hl[pp];
            float x = locx * (float)Wl[lev] - 0.5f;
            float y = locy * (float)Hl[lev] - 0.5f;
            float x0f = floorf(x), y0f = floorf(y);
            float fx = x - x0f, fy = y - y0f;
            int ix0 = (int)x0f, iy0 = (int)y0f;
            int ix1 = ix0 + 1, iy1 = iy0 + 1;
            bool vx0 = (ix0 >= 0) & (ix0 < Wl[lev]);
            bool vx1 = (ix1 >= 0) & (ix1 < Wl[lev]);
            bool vy0 = (iy0 >= 0) & (iy0 < Hl[lev]);
            bool vy1 = (iy1 >= 0) & (iy1 < Hl[lev]);
            float a = sc[lp];
            int b0 = stl[lev] + iy0 * Wl[lev];
            int b1 = stl[lev] + iy1 * Wl[lev];
            if (vx0 & vy0) wb[b0 + ix0] += a * (1.f - fx) * (1.f - fy);
            if (vx1 & vy0) wb[b0 + ix1] += a * fx * (1.f - fy);
            if (vx0 & vy1) wb[b1 + ix0] += a * (1.f - fx) * fy;
            if (vx1 & vy1) wb[b1 + ix1] += a * fx * fy;
        }
    }
    __syncthreads();

    // ---- phase 5: out[q, w*32+c] = wsum @ value^T  (MFMA, K=32 zero-padded) ----
    {
        short8 bfr[2];
#pragma unroll
        for (int nt = 0; nt < 2; ++nt)
            bfr[nt] = *(const short8*)&sVT[(w * 32 + nt * 16 + lrow) * LDSTR + lk];
        float4_ acc2[4][2];
#pragma unroll
        for (int i = 0; i < 4; ++i)
#pragma unroll
            for (int j = 0; j < 2; ++j) acc2[i][j] = (float4_)0.f;
#pragma unroll
        for (int mt = 0; mt < 4; ++mt) {
            union AfU { short8 v; uint32_t u[4]; } af;
            if (lk < 16) {
                const float* ab = sW + (size_t)((w << 6) + mt * 16 + lrow) * 17 + lk;
                af.u[0] = (uint32_t)f2bf(ab[0]) | ((uint32_t)f2bf(ab[1]) << 16);
                af.u[1] = (uint32_t)f2bf(ab[2]) | ((uint32_t)f2bf(ab[3]) << 16);
                af.u[2] = (uint32_t)f2bf(ab[4]) | ((uint32_t)f2bf(ab[5]) << 16);
                af.u[3] = (uint32_t)f2bf(ab[6]) | ((uint32_t)f2bf(ab[7]) << 16);
            } else {
                af.u[0] = 0; af.u[1] = 0; af.u[2] = 0; af.u[3] = 0;
            }
#pragma unroll
            for (int nt = 0; nt < 2; ++nt)
                acc2[mt][nt] = __builtin_amdgcn_mfma_f32_16x16x32_bf16(
                    af.v, bfr[nt], acc2[mt][nt], 0, 0, 0);
        }
#pragma unroll
        for (int mt = 0; mt < 4; ++mt)
#pragma unroll
            for (int nt = 0; nt < 2; ++nt)
#pragma unroll
                for (int r = 0; r < 4; ++r)
                    out[(size_t)(qbase + mt * 16 + (l >> 4) * 4 + r) * 256
                        + w * 32 + nt * 16 + lrow] = acc2[mt][nt][r];
    }
}

extern "C" void kernel_launch(void* const* d_in, const int* in_sizes, int n_in,
                              void* d_out, int out_size, void* d_ws, size_t ws_size,
                              hipStream_t stream) {
    (void)in_sizes; (void)n_in; (void)out_size; (void)ws_size;
    const float* query = (const float*)d_in[0];
    const float* key   = (const float*)d_in[1];
    const float* value = (const float*)d_in[2];
    const float* refp  = (const float*)d_in[3];
    const int*   ss    = (const int*)d_in[4];
    const float* Wso   = (const float*)d_in[5];
    const float* bso   = (const float*)d_in[6];
    uint16_t* WTb = (uint16_t*)d_ws;

    hipLaunchKernelGGL(k_transpose, dim3(256), dim3(256), 0, stream, Wso, WTb);
    hipLaunchKernelGGL(k_fused, dim3(625), dim3(512), 0, stream,
                       query, key, value, refp, ss, WTb, bso, (float*)d_out);
}

// Round 3
// 70.512 us; speedup vs baseline: 2.1174x; 1.2327x over previous
//
#include <hip/hip_runtime.h>
#include <hip/hip_bf16.h>
#include <stdint.h>

// MSDeformableAttention3D fused: bs=1, nq=40000=625*64, embed=256, H=8, L=4, P=4,
// 16 value rows (14 used: sum HW = 2+4+6+2), d=32. Block = 64 queries, 512 thr.
// spatial_shapes is static problem structure: (h,w) = (1,2),(2,2),(2,3),(1,2).
//
// LDS (32768 B, time-multiplexed with barriers):
//   [0,25600):  GEMM sA[64][40] + sB[256][40] bf16          (phase 2)
//   [0,32768):  sOff [64][256] bf16, XOR-swizzled            (phase 3-4a)
//   [0,24576):  wsFrag [512][48B] bf16 A-fragments           (phase 4b-5)
//
// Phases: 2) off=q@W_so+b (bf16 MFMA)  3) epilogue->sOff + fp32 scores/softmax
// 4) sampling -> register ws[14] bins (compile-time cell select)  5) MFMA
// wsum @ value (B-frags from global in regs) -> out.

typedef __attribute__((ext_vector_type(8))) short short8;
typedef __attribute__((ext_vector_type(4))) float float4_;

#define SB_OFF 5120
#define LDSTR 40
#define SMEM_BYTES 32768

static __device__ __forceinline__ uint16_t f2bf(float f) {
    union { float f; uint32_t u; } a; a.f = f;
    uint32_t r = a.u + 0x7fffu + ((a.u >> 16) & 1u);   // RNE
    return (uint16_t)(r >> 16);
}
static __device__ __forceinline__ float bf2f(uint16_t b) {
    union { uint32_t u; float f; } a; a.u = ((uint32_t)b) << 16;
    return a.f;
}

// outer-product scatter into compile-time bins; OOB corners match no cell.
template <int H_, int W_, int ST_>
static __device__ __forceinline__ void scatter(float* ws, float a, float x, float y) {
    float x0f = floorf(x), y0f = floorf(y);
    float fx = x - x0f, fy = y - y0f;
    int ix0 = (int)x0f, iy0 = (int)y0f;
    float xc[W_], yc[H_];
#pragma unroll
    for (int cx = 0; cx < W_; ++cx)
        xc[cx] = (ix0 == cx) ? (1.f - fx) : ((ix0 + 1 == cx) ? fx : 0.f);
#pragma unroll
    for (int cy = 0; cy < H_; ++cy)
        yc[cy] = ((iy0 == cy) ? (1.f - fy) : ((iy0 + 1 == cy) ? fy : 0.f)) * a;
#pragma unroll
    for (int cy = 0; cy < H_; ++cy)
#pragma unroll
        for (int cx = 0; cx < W_; ++cx)
            ws[ST_ + cy * W_ + cx] += xc[cx] * yc[cy];
}

// ---------------- W_so^T as bf16 (256x256) ----------------
__global__ __launch_bounds__(256) void k_transpose(const float* __restrict__ W,
                                                   uint16_t* __restrict__ WTb) {
    int n = blockIdx.x, k = threadIdx.x;
    WTb[n * 256 + k] = f2bf(W[k * 256 + n]);
}

// ---------------- fused kernel ----------------
__global__ __launch_bounds__(512, 4) void k_fused(const float* __restrict__ q,
                                                  const float* __restrict__ key,
                                                  const float* __restrict__ value,
                                                  const float* __restrict__ refp,
                                                  const uint16_t* __restrict__ WTb,
                                                  const float* __restrict__ bso,
                                                  float* __restrict__ out) {
    __shared__ __align__(16) char smem[SMEM_BYTES];
    short* sA = (short*)smem;
    short* sB = (short*)(smem + SB_OFF);

    int t = threadIdx.x;
    int w = t >> 6, l = t & 63;
    int qbase = blockIdx.x * 64;
    int qa = qbase + l;
    int g = l >> 4, lrow = l & 15, lk = g * 8;

    // ---- phase 2: off-GEMM 64x256, bf16 MFMA ----
    int wm = w >> 2, wn = w & 3;
    int ar = t >> 3, ak = t & 7;         // A staging
    int bn = t >> 1, bh = (t & 1) * 16;  // B staging
    float4_ acc[2][4];
#pragma unroll
    for (int i = 0; i < 2; ++i)
#pragma unroll
        for (int j = 0; j < 4; ++j) acc[i][j] = (float4_)0.f;

    for (int ks = 0; ks < 8; ++ks) {
        __syncthreads();
        {   // A: 64x32 fp32 -> bf16
            float4_ v = *(const float4_*)(q + (size_t)(qbase + ar) * 256 + ks * 32 + ak * 4);
            uint32_t p0 = (uint32_t)f2bf(v.x) | ((uint32_t)f2bf(v.y) << 16);
            uint32_t p1 = (uint32_t)f2bf(v.z) | ((uint32_t)f2bf(v.w) << 16);
            uint32_t* dst = (uint32_t*)&sA[ar * LDSTR + ak * 4];
            dst[0] = p0; dst[1] = p1;
        }
        {   // B: 256x32 bf16 copy
            const short8* src = (const short8*)(WTb + bn * 256 + ks * 32 + bh);
            *(short8*)&sB[bn * LDSTR + bh]     = src[0];
            *(short8*)&sB[bn * LDSTR + bh + 8] = src[1];
        }
        __syncthreads();
        short8 af[2], bf[4];
#pragma unroll
        for (int mi = 0; mi < 2; ++mi)
            af[mi] = *(const short8*)&sA[(wm * 32 + mi * 16 + lrow) * LDSTR + lk];
#pragma unroll
        for (int ni = 0; ni < 4; ++ni)
            bf[ni] = *(const short8*)&sB[(wn * 64 + ni * 16 + lrow) * LDSTR + lk];
#pragma unroll
        for (int mi = 0; mi < 2; ++mi)
#pragma unroll
            for (int ni = 0; ni < 4; ++ni)
                acc[mi][ni] = __builtin_amdgcn_mfma_f32_16x16x32_bf16(
                    af[mi], bf[ni], acc[mi][ni], 0, 0, 0);
    }
    __syncthreads();   // frag reads done block-wide before sOff overwrites sA/sB

    // ---- phase 3a: epilogue -> sOff (swizzled [64][256] bf16) ----
#pragma unroll
    for (int mi = 0; mi < 2; ++mi)
#pragma unroll
        for (int ni = 0; ni < 4; ++ni) {
            int col = wn * 64 + ni * 16 + lrow;
            float b = bso[col];
            int qrow = wm * 32 + mi * 16 + g * 4;
#pragma unroll
            for (int r = 0; r < 4; ++r) {
                int row = qrow + r;
                *(uint16_t*)(smem + row * 512 + ((col * 2) ^ ((row & 7) << 4))) =
                    f2bf(acc[mi][ni][r] + b);
            }
        }

    // ---- phase 3b: fp32 scores (lane=query, wave=head) + in-lane softmax ----
    float sc[16];
    {
        const float4_* qp = (const float4_*)(q + (size_t)qa * 256 + w * 32);
        float4_ qv[8];
#pragma unroll
        for (int j = 0; j < 8; ++j) qv[j] = qp[j];
#pragma unroll
        for (int kk = 0; kk < 16; ++kk) {
            const float4_* kp = (const float4_*)(key + kk * 256 + w * 32);
            float a = 0.f;
#pragma unroll
            for (int j = 0; j < 8; ++j) {
                float4_ kv = kp[j];
                a += qv[j].x * kv.x + qv[j].y * kv.y + qv[j].z * kv.z + qv[j].w * kv.w;
            }
            sc[kk] = a;
        }
        float m = sc[0];
#pragma unroll
        for (int kk = 1; kk < 16; ++kk) m = fmaxf(m, sc[kk]);
        float s = 0.f;
#pragma unroll
        for (int kk = 0; kk < 16; ++kk) { sc[kk] = __expf(sc[kk] - m); s += sc[kk]; }
        float inv = 1.f / s;
#pragma unroll
        for (int kk = 0; kk < 16; ++kk) sc[kk] *= inv;
    }
    __syncthreads();

    // ---- phase 4a: read offsets + value frags, sample into register bins ----
    union OvU { short8 v; short s[8]; } ov[4];
#pragma unroll
    for (int i = 0; i < 4; ++i)
        ov[i].v = *(const short8*)(smem + l * 512 + ((w * 64 + i * 16) ^ ((l & 7) << 4)));

    union VbU { short8 v; uint16_t u[8]; } vb[2];
#pragma unroll
    for (int nt = 0; nt < 2; ++nt) {
        if (g < 2) {
            int col = w * 32 + nt * 16 + lrow;
#pragma unroll
            for (int j = 0; j < 8; ++j)
                vb[nt].u[j] = f2bf(value[(g * 8 + j) * 256 + col]);
        } else {
#pragma unroll
            for (int j = 0; j < 8; ++j) vb[nt].u[j] = 0;
        }
    }

    float4_ r01 = *(const float4_*)(refp + (size_t)qa * 8);
    float4_ r23 = *(const float4_*)(refp + (size_t)qa * 8 + 4);
    float rx[4] = {r01.x, r01.z, r23.x, r23.z};
    float ry[4] = {r01.y, r01.w, r23.y, r23.w};

    float ws[14];
#pragma unroll
    for (int j = 0; j < 14; ++j) ws[j] = 0.f;

    // norm by (W,H)[pp]: W={2,2,3,2}, H={1,2,2,1}; sample grid by lev.
#define SAMPLE_LP(LP, PP, GH, GW, ST, NW, NH)                                 \
    {                                                                         \
        float ox = bf2f((uint16_t)ov[(2 * (LP)) >> 3].s[(2 * (LP)) & 7]);     \
        float oy = bf2f((uint16_t)ov[(2 * (LP) + 1) >> 3].s[(2 * (LP) + 1) & 7]); \
        float x = (rx[PP] + ox * (NW)) * (float)(GW)-0.5f;                    \
        float y = (ry[PP] + oy * (NH)) * (float)(GH)-0.5f;                    \
        scatter<GH, GW, ST>(ws, sc[LP], x, y);                                \
    }
    SAMPLE_LP(0, 0, 1, 2, 0, 0.5f, 1.0f)
    SAMPLE_LP(1, 1, 1, 2, 0, 0.5f, 0.5f)
    SAMPLE_LP(2, 2, 1, 2, 0, (1.f / 3.f), 0.5f)
    SAMPLE_LP(3, 3, 1, 2, 0, 0.5f, 1.0f)
    SAMPLE_LP(4, 0, 2, 2, 2, 0.5f, 1.0f)
    SAMPLE_LP(5, 1, 2, 2, 2, 0.5f, 0.5f)
    SAMPLE_LP(6, 2, 2, 2, 2, (1.f / 3.f), 0.5f)
    SAMPLE_LP(7, 3, 2, 2, 2, 0.5f, 1.0f)
    SAMPLE_LP(8, 0, 2, 3, 6, 0.5f, 1.0f)
    SAMPLE_LP(9, 1, 2, 3, 6, 0.5f, 0.5f)
    SAMPLE_LP(10, 2, 2, 3, 6, (1.f / 3.f), 0.5f)
    SAMPLE_LP(11, 3, 2, 3, 6, 0.5f, 1.0f)
    SAMPLE_LP(12, 0, 1, 2, 12, 0.5f, 1.0f)
    SAMPLE_LP(13, 1, 1, 2, 12, 0.5f, 0.5f)
    SAMPLE_LP(14, 2, 1, 2, 12, (1.f / 3.f), 0.5f)
    SAMPLE_LP(15, 3, 1, 2, 12, 0.5f, 1.0f)
#undef SAMPLE_LP

    __syncthreads();   // everyone done reading sOff

    // ---- phase 4b: pack ws -> wsFrag [512][48B] (bins 14,15 = 0) ----
    {
        union PkU { uint32_t u[8]; short8 v2[2]; } pk;
#pragma unroll
        for (int j = 0; j < 7; ++j)
            pk.u[j] = (uint32_t)f2bf(ws[2 * j]) | ((uint32_t)f2bf(ws[2 * j + 1]) << 16);
        pk.u[7] = 0;
        *(short8*)(smem + t * 48)      = pk.v2[0];
        *(short8*)(smem + t * 48 + 16) = pk.v2[1];
    }
    __syncthreads();

    // ---- phase 5: out = wsum @ value (per-head 64x32 MFMA) ----
    {
        union ZU { uint32_t u[4]; short8 v; } az;
        az.u[0] = 0; az.u[1] = 0; az.u[2] = 0; az.u[3] = 0;
        float4_ acc2[4][2];
#pragma unroll
        for (int i = 0; i < 4; ++i)
#pragma unroll
            for (int j = 0; j < 2; ++j) acc2[i][j] = (float4_)0.f;
#pragma unroll
        for (int mt = 0; mt < 4; ++mt) {
            short8 af = (g < 2)
                ? *(const short8*)(smem + (w * 64 + mt * 16 + lrow) * 48 + g * 16)
                : az.v;
#pragma unroll
            for (int nt = 0; nt < 2; ++nt)
                acc2[mt][nt] = __builtin_amdgcn_mfma_f32_16x16x32_bf16(
                    af, vb[nt].v, acc2[mt][nt], 0, 0, 0);
        }
#pragma unroll
        for (int mt = 0; mt < 4; ++mt)
#pragma unroll
            for (int nt = 0; nt < 2; ++nt)
#pragma unroll
                for (int r = 0; r < 4; ++r)
                    out[(size_t)(qbase + mt * 16 + g * 4 + r) * 256
                        + w * 32 + nt * 16 + lrow] = acc2[mt][nt][r];
    }
}

extern "C" void kernel_launch(void* const* d_in, const int* in_sizes, int n_in,
                              void* d_out, int out_size, void* d_ws, size_t ws_size,
                              hipStream_t stream) {
    (void)in_sizes; (void)n_in; (void)out_size; (void)ws_size;
    const float* query = (const float*)d_in[0];
    const float* key   = (const float*)d_in[1];
    const float* value = (const float*)d_in[2];
    const float* refp  = (const float*)d_in[3];
    const float* Wso   = (const float*)d_in[5];
    const float* bso   = (const float*)d_in[6];
    uint16_t* WTb = (uint16_t*)d_ws;

    hipLaunchKernelGGL(k_transpose, dim3(256), dim3(256), 0, stream, Wso, WTb);
    hipLaunchKernelGGL(k_fused, dim3(625), dim3(512), 0, stream,
                       query, key, value, refp, WTb, bso, (float*)d_out);
}